// Round 1
// baseline (6484.245 us; speedup 1.0000x reference)
//
#include <hip/hip_runtime.h>
#include <math.h>

#define NN   29040
#define NLAT 121
#define NLON 240
#define HD   128
#define LVN  11
#define EE   464640

// ---------------- edge kernel: one edge per thread ----------------
__global__ __launch_bounds__(256, 1)
void edge_kernel(const float* __restrict__ h,
                 const float* __restrict__ u,
                 const float* __restrict__ v,
                 const float* __restrict__ ea,
                 const float* __restrict__ We1, const float* __restrict__ be1,
                 const float* __restrict__ We2, const float* __restrict__ be2,
                 const float* __restrict__ Wc1, const float* __restrict__ bc1,
                 const float* __restrict__ Wcl,
                 const int* __restrict__ eidx,
                 float* __restrict__ agg,    // [NN,HD]  (d_out h-region, zeroed)
                 float* __restrict__ aggu,   // [NN,LVN]
                 float* __restrict__ aggv,   // [NN,LVN]
                 float* __restrict__ cnt)    // [NN]
{
    int e = blockIdx.x * 256 + threadIdx.x;
    if (e >= EE) return;
    int row = eidx[e];
    int col = eidx[EE + e];

    // ---- coord2radial ----
    float wd[33];
    float ucn = 0.f, vcn = 0.f;
#pragma unroll
    for (int l = 0; l < LVN; ++l) {
        float uc = u[col * LVN + l], vc = v[col * LVN + l];
        float ur = u[row * LVN + l], vr = v[row * LVN + l];
        float cs = sqrtf(uc * uc + vc * vc);
        float rs = sqrtf(ur * ur + vr * vr);
        wd[l]      = (uc * ur + vc * vr) / (cs * rs);
        wd[11 + l] = cs;
        wd[22 + l] = rs;
        ucn += uc * uc;
        vcn += vc * vc;
    }
    float radu = sqrtf(ucn), radv = sqrtf(vcn);

    // ---- edge MLP layer 1: acc = be1 + edge_in @ We1 ----
    float acc[HD];
#pragma unroll
    for (int j = 0; j < HD; ++j) acc[j] = be1[j];

    // w_diff rows (256..288)  -- done first so wd[] dies early
#pragma unroll
    for (int k = 0; k < 33; ++k) {
        float x = wd[k];
        const float* w = We1 + (size_t)(256 + k) * HD;
#pragma unroll
        for (int j = 0; j < HD; ++j) acc[j] = fmaf(x, w[j], acc[j]);
    }
    // edge_attr row (289)
    {
        float x = ea[e];
        const float* w = We1 + (size_t)289 * HD;
#pragma unroll
        for (int j = 0; j < HD; ++j) acc[j] = fmaf(x, w[j], acc[j]);
    }
    // h[row] rows (0..127)
    for (int k = 0; k < HD; ++k) {
        float x = h[(size_t)row * HD + k];
        const float* w = We1 + (size_t)k * HD;
#pragma unroll
        for (int j = 0; j < HD; ++j) acc[j] = fmaf(x, w[j], acc[j]);
    }
    // h[col] rows (128..255)
    for (int k = 0; k < HD; ++k) {
        float x = h[(size_t)col * HD + k];
        const float* w = We1 + (size_t)(HD + k) * HD;
#pragma unroll
        for (int j = 0; j < HD; ++j) acc[j] = fmaf(x, w[j], acc[j]);
    }
#pragma unroll
    for (int j = 0; j < HD; ++j) acc[j] = fmaxf(acc[j], 0.f);

    // ---- edge MLP layer 2: ef = relu(be2 + acc @ We2) ----
    float ef[HD];
#pragma unroll
    for (int j = 0; j < HD; ++j) ef[j] = be2[j];
    for (int k = 0; k < HD; ++k) {
        float x = acc[k];
        const float* w = We2 + (size_t)k * HD;
#pragma unroll
        for (int j = 0; j < HD; ++j) ef[j] = fmaf(x, w[j], ef[j]);
    }
#pragma unroll
    for (int j = 0; j < HD; ++j) ef[j] = fmaxf(ef[j], 0.f);

    // ---- scatter: agg += ef,  cnt += 1 ----
#pragma unroll
    for (int j = 0; j < HD; ++j) atomicAdd(&agg[(size_t)row * HD + j], ef[j]);
    atomicAdd(&cnt[row], 1.0f);

    // ---- coord MLP: c1 = relu(bc1 + ef @ Wc1)  (reuse acc) ----
#pragma unroll
    for (int j = 0; j < HD; ++j) acc[j] = bc1[j];
    for (int k = 0; k < HD; ++k) {
        float x = ef[k];
        const float* w = Wc1 + (size_t)k * HD;
#pragma unroll
        for (int j = 0; j < HD; ++j) acc[j] = fmaf(x, w[j], acc[j]);
    }
#pragma unroll
    for (int j = 0; j < HD; ++j) acc[j] = fmaxf(acc[j], 0.f);

    // ---- efc = c1 @ Wcl  -> [2][11];  wind = efc * rad2 ----
    float o22[22];
#pragma unroll
    for (int j = 0; j < 22; ++j) o22[j] = 0.f;
    for (int k = 0; k < HD; ++k) {
        float x = acc[k];
        const float* w = Wcl + (size_t)k * 22;
#pragma unroll
        for (int j = 0; j < 22; ++j) o22[j] = fmaf(x, w[j], o22[j]);
    }
#pragma unroll
    for (int l = 0; l < LVN; ++l) {
        atomicAdd(&aggu[(size_t)row * LVN + l], o22[l] * radu);
        atomicAdd(&aggv[(size_t)row * LVN + l], o22[11 + l] * radv);
    }
}

// ---------------- lat-band mean over longitude ----------------
__global__ __launch_bounds__(256)
void lat_kernel(const float* __restrict__ agg, float* __restrict__ lat)
{
    int t = blockIdx.x * 256 + threadIdx.x;   // t = i*HD + j
    if (t >= NLAT * HD) return;
    int i = t / HD, j = t % HD;
    float s = 0.f;
    for (int lon = 0; lon < NLON; ++lon)
        s += agg[((size_t)i * NLON + lon) * HD + j];
    lat[t] = s * (1.0f / NLON);
}

// ---------------- node kernel: MLP + residual + coord finalize ----------------
__global__ __launch_bounds__(256, 1)
void node_kernel(const float* __restrict__ h,
                 const float* __restrict__ Wn1, const float* __restrict__ bn1,
                 const float* __restrict__ Wn2, const float* __restrict__ bn2,
                 const float* __restrict__ lat,
                 const float* __restrict__ cnt,
                 float* __restrict__ hout,   // in: agg, out: h_out (same region)
                 float* __restrict__ aggu,
                 float* __restrict__ aggv)
{
    int n = blockIdx.x * 256 + threadIdx.x;
    if (n >= NN) return;
    int li = n / NLON;

    float acc[HD];
#pragma unroll
    for (int j = 0; j < HD; ++j) acc[j] = bn1[j];
    // h part (rows 0..127)
    for (int k = 0; k < HD; ++k) {
        float x = h[(size_t)n * HD + k];
        const float* w = Wn1 + (size_t)k * HD;
#pragma unroll
        for (int j = 0; j < HD; ++j) acc[j] = fmaf(x, w[j], acc[j]);
    }
    // agg part (rows 128..255)
    for (int k = 0; k < HD; ++k) {
        float x = hout[(size_t)n * HD + k];
        const float* w = Wn1 + (size_t)(HD + k) * HD;
#pragma unroll
        for (int j = 0; j < HD; ++j) acc[j] = fmaf(x, w[j], acc[j]);
    }
    // lat_agg part (rows 256..383)
    for (int k = 0; k < HD; ++k) {
        float x = lat[(size_t)li * HD + k];
        const float* w = Wn1 + (size_t)(2 * HD + k) * HD;
#pragma unroll
        for (int j = 0; j < HD; ++j) acc[j] = fmaf(x, w[j], acc[j]);
    }
#pragma unroll
    for (int j = 0; j < HD; ++j) acc[j] = fmaxf(acc[j], 0.f);

    float o[HD];
#pragma unroll
    for (int j = 0; j < HD; ++j) o[j] = bn2[j];
    for (int k = 0; k < HD; ++k) {
        float x = acc[k];
        const float* w = Wn2 + (size_t)k * HD;
#pragma unroll
        for (int j = 0; j < HD; ++j) o[j] = fmaf(x, w[j], o[j]);
    }
#pragma unroll
    for (int j = 0; j < HD; ++j)
        hout[(size_t)n * HD + j] = o[j] + h[(size_t)n * HD + j];

    // coord finalize: divide by cnt, clip
    float c = fmaxf(cnt[n], 1.0f);
#pragma unroll
    for (int l = 0; l < LVN; ++l) {
        float xu = aggu[(size_t)n * LVN + l] / c;
        float xv = aggv[(size_t)n * LVN + l] / c;
        xu = fminf(fmaxf(xu, -100.f), 100.f);
        xv = fminf(fmaxf(xv, -100.f), 100.f);
        aggu[(size_t)n * LVN + l] = xu;
        aggv[(size_t)n * LVN + l] = xv;
    }
}

extern "C" void kernel_launch(void* const* d_in, const int* in_sizes, int n_in,
                              void* d_out, int out_size, void* d_ws, size_t ws_size,
                              hipStream_t stream)
{
    const float* h   = (const float*)d_in[0];
    const float* u   = (const float*)d_in[1];
    const float* v   = (const float*)d_in[2];
    const float* ea  = (const float*)d_in[3];
    const float* We1 = (const float*)d_in[4];
    const float* be1 = (const float*)d_in[5];
    const float* We2 = (const float*)d_in[6];
    const float* be2 = (const float*)d_in[7];
    const float* Wn1 = (const float*)d_in[8];
    const float* bn1 = (const float*)d_in[9];
    const float* Wn2 = (const float*)d_in[10];
    const float* bn2 = (const float*)d_in[11];
    const float* Wc1 = (const float*)d_in[12];
    const float* bc1 = (const float*)d_in[13];
    const float* Wcl = (const float*)d_in[14];
    const int*   eidx = (const int*)d_in[15];

    float* out  = (float*)d_out;
    float* agg  = out;                       // [NN,HD]: agg accum, then h_out
    float* aggu = out + (size_t)NN * HD;     // [NN,LVN]
    float* aggv = aggu + (size_t)NN * LVN;   // [NN,LVN]

    float* cnt = (float*)d_ws;               // [NN]
    float* lat = cnt + NN;                   // [NLAT*HD]

    hipMemsetAsync(d_out, 0, (size_t)out_size * sizeof(float), stream);
    hipMemsetAsync(cnt, 0, (size_t)NN * sizeof(float), stream);

    edge_kernel<<<EE / 256, 256, 0, stream>>>(h, u, v, ea,
                                              We1, be1, We2, be2,
                                              Wc1, bc1, Wcl,
                                              eidx, agg, aggu, aggv, cnt);

    lat_kernel<<<(NLAT * HD + 255) / 256, 256, 0, stream>>>(agg, lat);

    node_kernel<<<(NN + 255) / 256, 256, 0, stream>>>(h, Wn1, bn1, Wn2, bn2,
                                                      lat, cnt, agg, aggu, aggv);
}